// Round 24
// baseline (226.848 us; speedup 1.0000x reference)
//
#include <hip/hip_runtime.h>
#include <math.h>

#define NTOK   2048
#define D      512
#define NV     100000
#define LOG2E  1.44269504f

typedef __attribute__((ext_vector_type(8)))  short bf16x8;
typedef __attribute__((ext_vector_type(16))) float f32x16;

// ---- strip geometry: 64 cols/block, single K-pass (both col-halves in LDS) ----
// seg strips: 157, 157, 469, 782  (bases 0, 157, 314, 783; total 1565)

// ---- workspace layout (bytes) ----
#define WS_FRAGS 0u           // 4 segs * 2048 * 512 * 2B = 8,388,608
#define WS_LISTS 8388608u     // 4 * 2048 * 4B = 32,768
#define WS_PART  8421376u     // 1565 * 2048 * 2B (bf16) = 6,410,240 (region 6,422,528)
#define WS_CUR   14843904u    // 16
#define WS_PAD   14843920u    // 16
#define WS_CL    14843936u    // 2048*3*4 = 24,576
#define WS_TGT   14868512u    // 2048*4   = 8,192
#define WS_ACC   14876704u    // 4*2049*4 = 32,784  (end 14,909,488)

__device__ __forceinline__ int cluster_of(int t){
  return (t < 10000) ? 0 : (t < 20000) ? 1 : (t < 50000) ? 2 : 3;
}
__device__ __forceinline__ bool is_root(int c){
  return c==5 || c==17 || c==123 || c==10005 || c==20007 || c==50011;
}
// f32 -> bf16 round-to-nearest-even
__device__ __forceinline__ unsigned short f2bf(float f){
  unsigned int u = __float_as_uint(f);
  u += 0x7fffu + ((u >> 16) & 1u);
  return (unsigned short)(u >> 16);
}
__device__ __forceinline__ float bf2f(unsigned short u){
  unsigned int v = ((unsigned int)u) << 16;
  return __uint_as_float(v);
}
__device__ __forceinline__ float fexp2(float x){
#if __has_builtin(__builtin_amdgcn_exp2f)
  return __builtin_amdgcn_exp2f(x);
#else
  return exp2f(x);
#endif
}

// ---------------------------------------------------------------------------
// K1 (+list build merged, r17-verified): per-token cluster logits + exact-f32
// target logit; lane 0 also appends the token to its segment list.
// ---------------------------------------------------------------------------
__global__ void k_token_logits(const float* __restrict__ hidden,
                               const float* __restrict__ weight,
                               const float* __restrict__ bias,
                               const float* __restrict__ cw,
                               const float* __restrict__ cb,
                               const int*   __restrict__ target,
                               float* __restrict__ cl_out,   // [2048][3]
                               float* __restrict__ tgt_out,  // [2048]
                               int*   __restrict__ lists,
                               int*   __restrict__ cursors)
{
  int wave = threadIdx.x >> 6;
  int lane = threadIdx.x & 63;
  int n = blockIdx.x * 4 + wave;
  if (n >= NTOK) return;
  const float* h = hidden + (size_t)n * D + lane * 8;
  int t = target[n];
  const float* wt = weight + (size_t)t * D + lane * 8;
  float hv[8];
  #pragma unroll
  for (int i = 0; i < 8; ++i) hv[i] = h[i];
  float acc[4] = {0.f, 0.f, 0.f, 0.f};
  #pragma unroll
  for (int j = 0; j < 3; ++j){
    const float* cwj = cw + j * D + lane * 8;
    float s = 0.f;
    #pragma unroll
    for (int i = 0; i < 8; ++i) s += hv[i] * cwj[i];
    acc[j] = s;
  }
  {
    float s = 0.f;
    #pragma unroll
    for (int i = 0; i < 8; ++i) s += hv[i] * wt[i];
    acc[3] = s;
  }
  #pragma unroll
  for (int m = 1; m < 64; m <<= 1){
    #pragma unroll
    for (int j = 0; j < 4; ++j) acc[j] += __shfl_xor(acc[j], m, 64);
  }
  if (lane == 0){
    cl_out[n*3+0] = acc[0] + cb[0];
    cl_out[n*3+1] = acc[1] + cb[1];
    cl_out[n*3+2] = acc[2] + cb[2];
    float tg = acc[3] + bias[t];
    if (is_root(t)) tg = -INFINITY;
    tgt_out[n] = tg;
    // merged list build
    lists[n] = n;                       // seg 0 identity
    int c = cluster_of(t);
    if (c > 0){
      int pos = atomicAdd(cursors + c, 1);
      lists[c * 2048 + pos] = n;
    }
  }
}

// ---------------------------------------------------------------------------
// K3: pad lists to multiples of 256 with sentinel token (=NTOK), write counts.
// ---------------------------------------------------------------------------
__global__ void k_pad_lists(int* __restrict__ lists, const int* __restrict__ cursors,
                            int* __restrict__ padded)
{
  if (threadIdx.x == 0) padded[0] = NTOK;
  for (int s = 1; s < 4; ++s){
    int c = cursors[s];
    int p = (c + 255) & ~255;
    if (threadIdx.x == 0) padded[s] = p;
    for (int i = c + threadIdx.x; i < p; i += blockDim.x)
      lists[s * 2048 + i] = NTOK;
  }
}

// ---------------------------------------------------------------------------
// K4: build bf16 A-fragments (hidden scaled by LOG2E so exp(x)=exp2(acc)).
// 2 k-slots per thread (ks and ks+16): 64B read, 2x16B write, 2 indep chains.
// elem offset = ((mf*32 + ks)*64 + lane)*8 ; row = mf*32+(lane&31),
// k = ks*16 + (lane>>5)*8 + j  (same k-convention as B).
// ---------------------------------------------------------------------------
__global__ void k_build_frags(const float* __restrict__ hidden,
                              const int*   __restrict__ lists,
                              const int*   __restrict__ padded,
                              unsigned short* __restrict__ frags)
{
  int tg   = blockIdx.x * 256 + threadIdx.x;   // [0, 4*65536)
  int seg  = tg >> 16;
  int s    = tg & 65535;
  int lane = s & 63;
  int ks0  = (s >> 6) & 15;
  int mf   = s >> 10;                          // 0..63
  int row  = mf * 32 + (lane & 31);
  if (row >= padded[seg]) return;
  int token = lists[seg * 2048 + row];
  #pragma unroll
  for (int p = 0; p < 2; ++p){
    int ks = ks0 + p * 16;
    unsigned int w[4];
    if (token < NTOK){
      const float* h = hidden + (size_t)token * D + ks * 16 + (lane >> 5) * 8;
      #pragma unroll
      for (int i = 0; i < 4; ++i){
        unsigned short lo = f2bf(h[2*i]   * LOG2E);
        unsigned short hi = f2bf(h[2*i+1] * LOG2E);
        w[i] = (unsigned int)lo | ((unsigned int)hi << 16);
      }
    } else {
      w[0] = w[1] = w[2] = w[3] = 0u;
    }
    size_t off = ((size_t)seg * 2048 * 512) + (((size_t)(mf * 32 + ks)) * 64 + lane) * 8;
    uint4 val; val.x = w[0]; val.y = w[1]; val.z = w[2]; val.w = w[3];
    *(uint4*)(frags + off) = val;
  }
}

// ---------------------------------------------------------------------------
// K5: Σexp GEMM (r23 verbatim — converged). Operand-swapped MFMA (reg axis =
// weight col, lane = token); bias·LOG2E folded as ks=32 MFMA with all-ones
// fragment; 512 threads; Bs-only 66 KB LDS; direct bf16 partials store.
// __launch_bounds__(512,4) = 128 VGPR cap, proven no-spill (VGPR 56).
// ---------------------------------------------------------------------------
__device__ __forceinline__ void epi2(const f32x16& a, const f32x16& b, int r0,
                                     int lane, unsigned short* __restrict__ pp)
{
  float s = 0.f;
  #pragma unroll
  for (int r = 0; r < 16; ++r) s += fexp2(a[r]) + fexp2(b[r]);
  s += __shfl_xor(s, 32, 64);       // combine the two reg-row halves
  if (lane < 32)
    pp[r0 + lane] = f2bf(s);        // write-once: direct bf16 partials store
}

__global__ __launch_bounds__(512, 4)
void k_gemm(const unsigned short* __restrict__ frags,
            const float* __restrict__ weight,
            const float* __restrict__ bias,
            const int*   __restrict__ padded,
            unsigned short* __restrict__ partials)   // [1565][2048] bf16
{
  __shared__ unsigned short Bs[528 * 64];      // 66 KB (64 cols x 33 ks-slots)

  int bid = blockIdx.x;
  int seg, strip0, colstart, colend;
  if      (bid < 157) { seg = 0; strip0 = 0;    colstart = 0;     colend = 10000;  }
  else if (bid < 314) { seg = 1; strip0 = 157;  colstart = 10000; colend = 20000;  }
  else if (bid < 783) { seg = 2; strip0 = 314;  colstart = 20000; colend = 50000;  }
  else                { seg = 3; strip0 = 783;  colstart = 50000; colend = 100000; }
  int col_base = colstart + (bid - strip0) * 64;

  int tid   = threadIdx.x;
  int wave  = tid >> 6;            // 0..7
  int lane  = tid & 63;
  int hi    = lane >> 5;
  int M = padded[seg];
  const unsigned short* fseg = frags + (size_t)seg * 2048 * 512;
  unsigned short* pp = partials + (size_t)bid * 2048;

  // ---- load B strip: 64 cols x 512 k, f32 -> bf16, frag-native LDS ----
  for (int it = 0; it < 16; ++it){
    int id  = it * 512 + tid;               // [0, 8192)
    int col = id >> 7;                      // 0..63
    int k0  = (id & 127) * 4;               // 0..508
    int cg  = col_base + col;
    float4 v = make_float4(0.f, 0.f, 0.f, 0.f);
    if (cg < colend) v = *(const float4*)(weight + (size_t)cg * D + k0);
    unsigned int lo  = (unsigned int)f2bf(v.x) | ((unsigned int)f2bf(v.y) << 16);
    unsigned int hi2 = (unsigned int)f2bf(v.z) | ((unsigned int)f2bf(v.w) << 16);
    int ks = k0 >> 4, bhi = (k0 >> 3) & 1, j0 = k0 & 7;
    int off = ks * 2048 + (col >> 5) * 1024 + bhi * 512 + (col & 31) * 16 + j0 * 2;
    off ^= ((ks & 3) << 5) ^ (bhi << 4);
    uint2 pk; pk.x = lo; pk.y = hi2;
    *(uint2*)((char*)Bs + off) = pk;
  }
  // ---- stage bias row at ks=32: slot k_local=0 holds bias*LOG2E (or -inf) ----
  if (tid < 256){
    int col = tid >> 2;                     // 0..63
    int q   = tid & 3;
    int bhi = q >> 1;
    int j0  = (q & 1) * 4;
    int cg  = col_base + col;
    unsigned int x = 0u;
    if (bhi == 0 && j0 == 0){
      float bv = (cg < colend && !is_root(cg)) ? bias[cg] * LOG2E : -INFINITY;
      x = (unsigned int)f2bf(bv);           // low slot = bias, high slot = 0
    }
    int off = 32 * 2048 + (col >> 5) * 1024 + bhi * 512 + (col & 31) * 16 + j0 * 2;
    off ^= ((32 & 3) << 5) ^ (bhi << 4);
    uint2 pk; pk.x = x; pk.y = 0u;
    *(uint2*)((char*)Bs + off) = pk;
  }
  __syncthreads();   // B + bias ready

  const char* bsc = (const char*)Bs;
  int roff = (lane * 16) ^ (hi << 4);   // B read base; (ks&3)<<5 XOR per iter

  bf16x8 ones;
  #pragma unroll
  for (int j = 0; j < 8; ++j) ones[j] = (short)0x3F80;   // bf16 1.0

  for (int m0 = 0; m0 < M; m0 += 512){
    int r0 = m0 + wave * 64;
    if (r0 < M){
      f32x16 acc00, acc01, acc10, acc11;
      #pragma unroll
      for (int i = 0; i < 16; ++i){ acc00[i]=0.f; acc01[i]=0.f; acc10[i]=0.f; acc11[i]=0.f; }

      const unsigned short* pa0 = fseg + (size_t)(r0 >> 5) * 16384 + (size_t)lane * 8;
      const unsigned short* pa1 = pa0 + 16384;

      __builtin_amdgcn_s_setprio(1);     // T5: favor MFMA-issuing waves
      #pragma unroll 4
      for (int ks = 0; ks < 32; ++ks){
        bf16x8 a0 = *(const bf16x8*)(pa0 + ks * 512);
        bf16x8 a1 = *(const bf16x8*)(pa1 + ks * 512);
        int kb = ks * 2048 + (roff ^ ((ks & 3) << 5));
        bf16x8 b0 = *(const bf16x8*)(bsc + kb);
        bf16x8 b1 = *(const bf16x8*)(bsc + kb + 1024);
        // swapped operands: reg axis = weight col, lane axis = token
        acc00 = __builtin_amdgcn_mfma_f32_32x32x16_bf16(b0, a0, acc00, 0, 0, 0);
        acc01 = __builtin_amdgcn_mfma_f32_32x32x16_bf16(b1, a0, acc01, 0, 0, 0);
        acc10 = __builtin_amdgcn_mfma_f32_32x32x16_bf16(b0, a1, acc10, 0, 0, 0);
        acc11 = __builtin_amdgcn_mfma_f32_32x32x16_bf16(b1, a1, acc11, 0, 0, 0);
      }
      // bias step: Σ_k Bs[c][512+k]·1 = bias_c·LOG2E (or -inf)
      {
        int kb32 = 32 * 2048 + roff;
        bf16x8 bb0 = *(const bf16x8*)(bsc + kb32);
        bf16x8 bb1 = *(const bf16x8*)(bsc + kb32 + 1024);
        acc00 = __builtin_amdgcn_mfma_f32_32x32x16_bf16(bb0, ones, acc00, 0, 0, 0);
        acc01 = __builtin_amdgcn_mfma_f32_32x32x16_bf16(bb1, ones, acc01, 0, 0, 0);
        acc10 = __builtin_amdgcn_mfma_f32_32x32x16_bf16(bb0, ones, acc10, 0, 0, 0);
        acc11 = __builtin_amdgcn_mfma_f32_32x32x16_bf16(bb1, ones, acc11, 0, 0, 0);
      }
      __builtin_amdgcn_s_setprio(0);     // epilogue (exp2/VALU) at normal prio
      epi2(acc00, acc01, r0,      lane, pp);   // tokens r0..r0+31
      epi2(acc10, acc11, r0 + 32, lane, pp);   // tokens r0+32..r0+63
    }
  }
  // no trailing barrier / store pass: epi2 wrote partials directly
}

// ---------------------------------------------------------------------------
// K5b: reduce bf16 partials over strips of each segment, scatter via lists.
// ---------------------------------------------------------------------------
__global__ void k_reduce(const unsigned short* __restrict__ partials,
                         const int*   __restrict__ lists,
                         const int*   __restrict__ padded,
                         float* __restrict__ acc_out)     // [4][2049]
{
  int b   = blockIdx.x;          // 32 blocks: seg = b>>3, row chunk = b&7
  int seg = b >> 3;
  int row = (b & 7) * 256 + threadIdx.x;
  if (row >= padded[seg]) return;
  int base, cnt;
  if      (seg == 0){ base = 0;   cnt = 157; }
  else if (seg == 1){ base = 157; cnt = 157; }
  else if (seg == 2){ base = 314; cnt = 469; }
  else              { base = 783; cnt = 782; }
  float s = 0.f;
  int j = 0;
  for (; j + 4 <= cnt; j += 4){
    s += bf2f(partials[(size_t)(base + j    ) * 2048 + row]);
    s += bf2f(partials[(size_t)(base + j + 1) * 2048 + row]);
    s += bf2f(partials[(size_t)(base + j + 2) * 2048 + row]);
    s += bf2f(partials[(size_t)(base + j + 3) * 2048 + row]);
  }
  for (; j < cnt; ++j) s += bf2f(partials[(size_t)(base + j) * 2048 + row]);
  int token = lists[seg * 2048 + row];
  if (token < NTOK) acc_out[seg * 2049 + token] = s;
}

// ---------------------------------------------------------------------------
// K6: finalize NLL per token.
// ---------------------------------------------------------------------------
__global__ void k_finalize(const float* __restrict__ accs,   // [4][2049]
                           const float* __restrict__ cl,     // [2048][3]
                           const float* __restrict__ tgt,
                           const int*   __restrict__ target,
                           float* __restrict__ out)
{
  int n = blockIdx.x * blockDim.x + threadIdx.x;
  if (n >= NTOK) return;
  int c = cluster_of(target[n]);
  float e0 = __expf(cl[n*3+0]), e1 = __expf(cl[n*3+1]), e2 = __expf(cl[n*3+2]);
  float head_lse = __logf(accs[n] + e0 + e1 + e2);
  float nll;
  if (c == 0){
    nll = head_lse - tgt[n];
  } else {
    float tail_lse = __logf(accs[c * 2049 + n]);
    nll = head_lse + tail_lse - cl[n*3 + (3 - c)] - tgt[n];
  }
  out[n] = nll;
}

extern "C" void kernel_launch(void* const* d_in, const int* in_sizes, int n_in,
                              void* d_out, int out_size, void* d_ws, size_t ws_size,
                              hipStream_t stream)
{
  (void)in_sizes; (void)n_in; (void)out_size; (void)ws_size;
  const float* hidden = (const float*)d_in[0];
  const float* weight = (const float*)d_in[1];
  const float* bias   = (const float*)d_in[2];
  const float* cw     = (const float*)d_in[3];
  const float* cb     = (const float*)d_in[4];
  const int*   target = (const int*)d_in[5];
  float* out = (float*)d_out;
  char*  ws  = (char*)d_ws;

  unsigned short* frags    = (unsigned short*)(ws + WS_FRAGS);
  int*   lists    = (int*)(ws + WS_LISTS);
  unsigned short* partials = (unsigned short*)(ws + WS_PART);
  int*   cursors  = (int*)(ws + WS_CUR);
  int*   padded   = (int*)(ws + WS_PAD);
  float* cl       = (float*)(ws + WS_CL);
  float* tgt      = (float*)(ws + WS_TGT);
  float* acc      = (float*)(ws + WS_ACC);

  hipMemsetAsync(ws + WS_CUR, 0, 16, stream);   // cursors only

  k_token_logits<<<512, 256, 0, stream>>>(hidden, weight, bias, cw, cb, target,
                                          cl, tgt, lists, cursors);
  k_pad_lists   <<<1,   256, 0, stream>>>(lists, cursors, padded);
  k_build_frags <<<1024,256, 0, stream>>>(hidden, lists, padded, frags);
  k_gemm        <<<1565,512, 0, stream>>>(frags, weight, bias, padded, partials);
  k_reduce      <<<32,  256, 0, stream>>>(partials, lists, padded, acc);
  k_finalize    <<<8,   256, 0, stream>>>(acc, cl, tgt, target, out);
}

// Round 25
// 223.986 us; speedup vs baseline: 1.0128x; 1.0128x over previous
//
#include <hip/hip_runtime.h>
#include <math.h>

#define NTOK   2048
#define D      512
#define NV     100000
#define LOG2E  1.44269504f

typedef __attribute__((ext_vector_type(2)))  long  long2v;
typedef __attribute__((ext_vector_type(16))) float f32x16;

// ---- strip geometry: 64 cols/block, fp8 single K-pass ----
// seg strips: 157, 157, 469, 782  (bases 0, 157, 314, 783; total 1565)

// ---- workspace layout (bytes) ----
#define WS_FRAGS 0u           // fp8: 4 segs * 2048 * 512 * 1B = 4 MB (region 8 MB)
#define WS_LISTS 8388608u     // 4 * 2048 * 4B
#define WS_PART  8421376u     // 1565 * 2048 * 2B (bf16) = 6,410,240
#define WS_CUR   14843904u    // 16
#define WS_PAD   14843920u    // 16
#define WS_CL    14843936u    // 2048*3*4
#define WS_TGT   14868512u    // 2048*4
#define WS_ACC   14876704u    // 4*2049*4  (end 14,909,488)

__device__ __forceinline__ int cluster_of(int t){
  return (t < 10000) ? 0 : (t < 20000) ? 1 : (t < 50000) ? 2 : 3;
}
__device__ __forceinline__ bool is_root(int c){
  return c==5 || c==17 || c==123 || c==10005 || c==20007 || c==50011;
}
__device__ __forceinline__ unsigned short f2bf(float f){
  unsigned int u = __float_as_uint(f);
  u += 0x7fffu + ((u >> 16) & 1u);
  return (unsigned short)(u >> 16);
}
__device__ __forceinline__ float bf2f(unsigned short u){
  unsigned int v = ((unsigned int)u) << 16;
  return __uint_as_float(v);
}
__device__ __forceinline__ float fexp2(float x){
#if __has_builtin(__builtin_amdgcn_exp2f)
  return __builtin_amdgcn_exp2f(x);
#else
  return exp2f(x);
#endif
}
// f32 -> OCP e4m3fn, RNE, saturate to +-448, correct subnormals (2^-9 grid).
__device__ __forceinline__ unsigned int f2fp8(float x){
  unsigned int u = __float_as_uint(x);
  unsigned int s = (u >> 24) & 0x80u;
  float a = fabsf(x);
  if (!(a < 448.f)) return s | 0x7Eu;              // sat (and NaN -> max)
  if (a < 0.015625f){                              // < 2^-6: subnormal grid
    int m = __float2int_rn(a * 512.0f);            // 0..8 (8 == 2^-6 normal)
    return s | (unsigned int)m;
  }
  unsigned int au = u & 0x7FFFFFFFu;
  au += 0x7FFFFu + ((au >> 20) & 1u);              // RNE to 3 mantissa bits
  int e = (int)(au >> 23) - 127;                   // [-6, 8] after rounding
  unsigned int m = (au >> 20) & 7u;
  unsigned int enc = ((unsigned int)(e + 7) << 3) | m;
  if (enc > 0x7Eu) enc = 0x7Eu;                    // never emit NaN encoding
  return s | enc;
}

// ---------------------------------------------------------------------------
// K1 (+list build merged): per-token cluster logits + exact-f32 target logit;
// lane 0 appends the token to its segment list.
// ---------------------------------------------------------------------------
__global__ void k_token_logits(const float* __restrict__ hidden,
                               const float* __restrict__ weight,
                               const float* __restrict__ bias,
                               const float* __restrict__ cw,
                               const float* __restrict__ cb,
                               const int*   __restrict__ target,
                               float* __restrict__ cl_out,   // [2048][3]
                               float* __restrict__ tgt_out,  // [2048]
                               int*   __restrict__ lists,
                               int*   __restrict__ cursors)
{
  int wave = threadIdx.x >> 6;
  int lane = threadIdx.x & 63;
  int n = blockIdx.x * 4 + wave;
  if (n >= NTOK) return;
  const float* h = hidden + (size_t)n * D + lane * 8;
  int t = target[n];
  const float* wt = weight + (size_t)t * D + lane * 8;
  float hv[8];
  #pragma unroll
  for (int i = 0; i < 8; ++i) hv[i] = h[i];
  float acc[4] = {0.f, 0.f, 0.f, 0.f};
  #pragma unroll
  for (int j = 0; j < 3; ++j){
    const float* cwj = cw + j * D + lane * 8;
    float s = 0.f;
    #pragma unroll
    for (int i = 0; i < 8; ++i) s += hv[i] * cwj[i];
    acc[j] = s;
  }
  {
    float s = 0.f;
    #pragma unroll
    for (int i = 0; i < 8; ++i) s += hv[i] * wt[i];
    acc[3] = s;
  }
  #pragma unroll
  for (int m = 1; m < 64; m <<= 1){
    #pragma unroll
    for (int j = 0; j < 4; ++j) acc[j] += __shfl_xor(acc[j], m, 64);
  }
  if (lane == 0){
    cl_out[n*3+0] = acc[0] + cb[0];
    cl_out[n*3+1] = acc[1] + cb[1];
    cl_out[n*3+2] = acc[2] + cb[2];
    float tg = acc[3] + bias[t];
    if (is_root(t)) tg = -INFINITY;
    tgt_out[n] = tg;
    lists[n] = n;
    int c = cluster_of(t);
    if (c > 0){
      int pos = atomicAdd(cursors + c, 1);
      lists[c * 2048 + pos] = n;
    }
  }
}

// ---------------------------------------------------------------------------
// K3: pad lists to multiples of 256 with sentinel token (=NTOK), write counts.
// ---------------------------------------------------------------------------
__global__ void k_pad_lists(int* __restrict__ lists, const int* __restrict__ cursors,
                            int* __restrict__ padded)
{
  if (threadIdx.x == 0) padded[0] = NTOK;
  for (int s = 1; s < 4; ++s){
    int c = cursors[s];
    int p = (c + 255) & ~255;
    if (threadIdx.x == 0) padded[s] = p;
    for (int i = c + threadIdx.x; i < p; i += blockDim.x)
      lists[s * 2048 + i] = NTOK;
  }
}

// ---------------------------------------------------------------------------
// K4: build fp8 A-fragments (hidden scaled by LOG2E so exp(x)=exp2(acc)).
// Layout v2 (2 ks packed per 16B): byte off = ((mf*16 + kp)*64 + lane)*16,
// bytes[0..7] = ks=2kp (k = 32kp + hi*8 + j), bytes[8..15] = ks=2kp+1.
// ---------------------------------------------------------------------------
__global__ void k_build_frags(const float* __restrict__ hidden,
                              const int*   __restrict__ lists,
                              const int*   __restrict__ padded,
                              unsigned char* __restrict__ frags)
{
  int tg   = blockIdx.x * 256 + threadIdx.x;   // [0, 4*65536)
  int seg  = tg >> 16;
  int s    = tg & 65535;
  int lane = s & 63;
  int kp   = (s >> 6) & 15;
  int mf   = s >> 10;                          // 0..63
  int row  = mf * 32 + (lane & 31);
  if (row >= padded[seg]) return;
  int token = lists[seg * 2048 + row];
  int hi    = lane >> 5;
  unsigned int w[4] = {0u, 0u, 0u, 0u};
  if (token < NTOK){
    const float* h0 = hidden + (size_t)token * D + 32 * kp + hi * 8;        // ks=2kp
    const float* h1 = h0 + 16;                                              // ks=2kp+1
    #pragma unroll
    for (int g = 0; g < 2; ++g){
      unsigned int lo = f2fp8(h0[4*g+0]*LOG2E) | (f2fp8(h0[4*g+1]*LOG2E)<<8)
                      | (f2fp8(h0[4*g+2]*LOG2E)<<16) | (f2fp8(h0[4*g+3]*LOG2E)<<24);
      unsigned int hiw= f2fp8(h1[4*g+0]*LOG2E) | (f2fp8(h1[4*g+1]*LOG2E)<<8)
                      | (f2fp8(h1[4*g+2]*LOG2E)<<16) | (f2fp8(h1[4*g+3]*LOG2E)<<24);
      w[g] = lo; w[2+g] = hiw;
    }
  }
  size_t off = (size_t)seg * 1048576u + (((size_t)(mf * 16 + kp)) * 64 + lane) * 16;
  uint4 val; val.x = w[0]; val.y = w[1]; val.z = w[2]; val.w = w[3];
  *(uint4*)(frags + off) = val;
}

// ---------------------------------------------------------------------------
// K5: Σexp GEMM, fp8 (mfma_f32_32x32x16_fp8_fp8 at bf16 rate, half the
// operand bytes). Swapped operands (reg axis = weight col, lane = token);
// bias·LOG2E folded as extra slot consumed by an all-ones-A MFMA (masked
// cols get -448 -> exp2 underflows to 0). Per kp-step: 2 global A-loads +
// 2 LDS B-reads + 8 MFMAs (0.25 loads/MFMA, 2x better than bf16). Bs-only
// LDS = 34 KB -> 4 blocks/CU. Direct bf16 partials store (write-once).
// B LDS layout: kp*2048 + (col>>5)*1024 + ((col&31)+32*hi)*16 + ksub*8 + j;
// read is lane-linear (lane*16) -> contiguous 1KB per half, conflict-free.
// ---------------------------------------------------------------------------
__device__ __forceinline__ void epi2(const f32x16& a, const f32x16& b, int r0,
                                     int lane, unsigned short* __restrict__ pp)
{
  float s = 0.f;
  #pragma unroll
  for (int r = 0; r < 16; ++r) s += fexp2(a[r]) + fexp2(b[r]);
  s += __shfl_xor(s, 32, 64);       // combine the two reg-row halves
  if (lane < 32)
    pp[r0 + lane] = f2bf(s);        // write-once: direct bf16 partials store
}

__global__ __launch_bounds__(512, 4)
void k_gemm(const unsigned char* __restrict__ frags,
            const float* __restrict__ weight,
            const float* __restrict__ bias,
            const int*   __restrict__ padded,
            unsigned short* __restrict__ partials)   // [1565][2048] bf16
{
  __shared__ unsigned char Bs[34816];          // 34 KB: 16 kp * 2048 + bias 2048

  int bid = blockIdx.x;
  int seg, strip0, colstart, colend;
  if      (bid < 157) { seg = 0; strip0 = 0;    colstart = 0;     colend = 10000;  }
  else if (bid < 314) { seg = 1; strip0 = 157;  colstart = 10000; colend = 20000;  }
  else if (bid < 783) { seg = 2; strip0 = 314;  colstart = 20000; colend = 50000;  }
  else                { seg = 3; strip0 = 783;  colstart = 50000; colend = 100000; }
  int col_base = colstart + (bid - strip0) * 64;

  int tid   = threadIdx.x;
  int wave  = tid >> 6;            // 0..7
  int lane  = tid & 63;
  int M = padded[seg];
  const unsigned char* fseg = frags + (size_t)seg * 1048576u;
  unsigned short* pp = partials + (size_t)bid * 2048;

  // ---- load B strip: 64 cols x 512 k, f32 -> fp8, frag-native LDS ----
  for (int it = 0; it < 16; ++it){
    int id  = it * 512 + tid;               // [0, 8192)
    int col = id >> 7;                      // 0..63
    int k0  = (id & 127) * 4;               // 0..508
    int cg  = col_base + col;
    float4 v = make_float4(0.f, 0.f, 0.f, 0.f);
    if (cg < colend) v = *(const float4*)(weight + (size_t)cg * D + k0);
    unsigned int pk = f2fp8(v.x) | (f2fp8(v.y)<<8) | (f2fp8(v.z)<<16) | (f2fp8(v.w)<<24);
    int ks = k0 >> 4, kp = ks >> 1, ksub = ks & 1, kk = k0 & 15;
    int hi2 = kk >> 3, j0 = kk & 7;         // j0 in {0,4}
    int off = kp * 2048 + (col >> 5) * 1024 + ((col & 31) + 32 * hi2) * 16 + ksub * 8 + j0;
    *(unsigned int*)(Bs + off) = pk;
  }
  // ---- stage bias slot (region [32768, 34816)): 16B per (col, hi-part) ----
  if (tid < 128){
    int col  = tid & 63;
    int part = tid >> 6;                    // 0: k 0-7 slot (bias at j=0); 1: k 8-15 (zeros)
    int cg   = col_base + col;
    unsigned int x = 0u;
    if (part == 0){
      float bv = (cg < colend && !is_root(cg)) ? bias[cg] * LOG2E : -448.f;
      x = f2fp8(bv);                        // low byte; rest zero
    }
    int off = 32768 + (col >> 5) * 1024 + ((col & 31) + 32 * part) * 16;
    uint4 z; z.x = x; z.y = 0u; z.z = 0u; z.w = 0u;
    *(uint4*)(Bs + off) = z;
  }
  __syncthreads();   // B + bias ready

  const char* bsc = (const char*)Bs;
  int l16 = lane * 16;
  long ones8 = 0x3838383838383838L;         // 8x fp8 e4m3 1.0

  for (int m0 = 0; m0 < M; m0 += 512){
    int r0 = m0 + wave * 64;
    if (r0 < M){
      f32x16 acc00, acc01, acc10, acc11;
      #pragma unroll
      for (int i = 0; i < 16; ++i){ acc00[i]=0.f; acc01[i]=0.f; acc10[i]=0.f; acc11[i]=0.f; }

      const unsigned char* pa0 = fseg + (size_t)(r0 >> 5) * 16384 + (size_t)lane * 16;
      const unsigned char* pa1 = pa0 + 16384;

      __builtin_amdgcn_s_setprio(1);
      #pragma unroll 4
      for (int kp = 0; kp < 16; ++kp){
        long2v A0 = *(const long2v*)(pa0 + kp * 1024);
        long2v A1 = *(const long2v*)(pa1 + kp * 1024);
        long2v B0 = *(const long2v*)(bsc + kp * 2048 + l16);
        long2v B1 = *(const long2v*)(bsc + kp * 2048 + 1024 + l16);
        acc00 = __builtin_amdgcn_mfma_f32_32x32x16_fp8_fp8(B0[0], A0[0], acc00, 0, 0, 0);
        acc01 = __builtin_amdgcn_mfma_f32_32x32x16_fp8_fp8(B1[0], A0[0], acc01, 0, 0, 0);
        acc10 = __builtin_amdgcn_mfma_f32_32x32x16_fp8_fp8(B0[0], A1[0], acc10, 0, 0, 0);
        acc11 = __builtin_amdgcn_mfma_f32_32x32x16_fp8_fp8(B1[0], A1[0], acc11, 0, 0, 0);
        acc00 = __builtin_amdgcn_mfma_f32_32x32x16_fp8_fp8(B0[1], A0[1], acc00, 0, 0, 0);
        acc01 = __builtin_amdgcn_mfma_f32_32x32x16_fp8_fp8(B1[1], A0[1], acc01, 0, 0, 0);
        acc10 = __builtin_amdgcn_mfma_f32_32x32x16_fp8_fp8(B0[1], A1[1], acc10, 0, 0, 0);
        acc11 = __builtin_amdgcn_mfma_f32_32x32x16_fp8_fp8(B1[1], A1[1], acc11, 0, 0, 0);
      }
      // bias step: Σ_k biasRow[c][k] * 1 = bias_c*LOG2E (or -448)
      {
        long bb0 = *(const long*)(bsc + 32768 + l16);
        long bb1 = *(const long*)(bsc + 32768 + 1024 + l16);
        acc00 = __builtin_amdgcn_mfma_f32_32x32x16_fp8_fp8(bb0, ones8, acc00, 0, 0, 0);
        acc01 = __builtin_amdgcn_mfma_f32_32x32x16_fp8_fp8(bb1, ones8, acc01, 0, 0, 0);
        acc10 = __builtin_amdgcn_mfma_f32_32x32x16_fp8_fp8(bb0, ones8, acc10, 0, 0, 0);
        acc11 = __builtin_amdgcn_mfma_f32_32x32x16_fp8_fp8(bb1, ones8, acc11, 0, 0, 0);
      }
      __builtin_amdgcn_s_setprio(0);
      epi2(acc00, acc01, r0,      lane, pp);   // tokens r0..r0+31
      epi2(acc10, acc11, r0 + 32, lane, pp);   // tokens r0+32..r0+63
    }
  }
}

// ---------------------------------------------------------------------------
// K5b: reduce bf16 partials over strips of each segment, scatter via lists.
// ---------------------------------------------------------------------------
__global__ void k_reduce(const unsigned short* __restrict__ partials,
                         const int*   __restrict__ lists,
                         const int*   __restrict__ padded,
                         float* __restrict__ acc_out)     // [4][2049]
{
  int b   = blockIdx.x;          // 32 blocks: seg = b>>3, row chunk = b&7
  int seg = b >> 3;
  int row = (b & 7) * 256 + threadIdx.x;
  if (row >= padded[seg]) return;
  int base, cnt;
  if      (seg == 0){ base = 0;   cnt = 157; }
  else if (seg == 1){ base = 157; cnt = 157; }
  else if (seg == 2){ base = 314; cnt = 469; }
  else              { base = 783; cnt = 782; }
  float s = 0.f;
  int j = 0;
  for (; j + 4 <= cnt; j += 4){
    s += bf2f(partials[(size_t)(base + j    ) * 2048 + row]);
    s += bf2f(partials[(size_t)(base + j + 1) * 2048 + row]);
    s += bf2f(partials[(size_t)(base + j + 2) * 2048 + row]);
    s += bf2f(partials[(size_t)(base + j + 3) * 2048 + row]);
  }
  for (; j < cnt; ++j) s += bf2f(partials[(size_t)(base + j) * 2048 + row]);
  int token = lists[seg * 2048 + row];
  if (token < NTOK) acc_out[seg * 2049 + token] = s;
}

// ---------------------------------------------------------------------------
// K6: finalize NLL per token.
// ---------------------------------------------------------------------------
__global__ void k_finalize(const float* __restrict__ accs,   // [4][2049]
                           const float* __restrict__ cl,     // [2048][3]
                           const float* __restrict__ tgt,
                           const int*   __restrict__ target,
                           float* __restrict__ out)
{
  int n = blockIdx.x * blockDim.x + threadIdx.x;
  if (n >= NTOK) return;
  int c = cluster_of(target[n]);
  float e0 = __expf(cl[n*3+0]), e1 = __expf(cl[n*3+1]), e2 = __expf(cl[n*3+2]);
  float head_lse = __logf(accs[n] + e0 + e1 + e2);
  float nll;
  if (c == 0){
    nll = head_lse - tgt[n];
  } else {
    float tail_lse = __logf(accs[c * 2049 + n]);
    nll = head_lse + tail_lse - cl[n*3 + (3 - c)] - tgt[n];
  }
  out[n] = nll;
}

extern "C" void kernel_launch(void* const* d_in, const int* in_sizes, int n_in,
                              void* d_out, int out_size, void* d_ws, size_t ws_size,
                              hipStream_t stream)
{
  (void)in_sizes; (void)n_in; (void)out_size; (void)ws_size;
  const float* hidden = (const float*)d_in[0];
  const float* weight = (const float*)d_in[1];
  const float* bias   = (const float*)d_in[2];
  const float* cw     = (const float*)d_in[3];
  const float* cb     = (const float*)d_in[4];
  const int*   target = (const int*)d_in[5];
  float* out = (float*)d_out;
  char*  ws  = (char*)d_ws;

  unsigned char*  frags    = (unsigned char*)(ws + WS_FRAGS);
  int*   lists    = (int*)(ws + WS_LISTS);
  unsigned short* partials = (unsigned short*)(ws + WS_PART);
  int*   cursors  = (int*)(ws + WS_CUR);
  int*   padded   = (int*)(ws + WS_PAD);
  float* cl       = (float*)(ws + WS_CL);
  float* tgt      = (float*)(ws + WS_TGT);
  float* acc      = (float*)(ws + WS_ACC);

  hipMemsetAsync(ws + WS_CUR, 0, 16, stream);   // cursors only

  k_token_logits<<<512, 256, 0, stream>>>(hidden, weight, bias, cw, cb, target,
                                          cl, tgt, lists, cursors);
  k_pad_lists   <<<1,   256, 0, stream>>>(lists, cursors, padded);
  k_build_frags <<<1024,256, 0, stream>>>(hidden, lists, padded, frags);
  k_gemm        <<<1565,512, 0, stream>>>(frags, weight, bias, padded, partials);
  k_reduce      <<<32,  256, 0, stream>>>(partials, lists, padded, acc);
  k_finalize    <<<8,   256, 0, stream>>>(acc, cl, tgt, target, out);
}

// Round 26
// 208.143 us; speedup vs baseline: 1.0899x; 1.0761x over previous
//
#include <hip/hip_runtime.h>
#include <math.h>

#define NTOK   2048
#define D      512
#define NV     100000
#define LOG2E  1.44269504f

typedef __attribute__((ext_vector_type(2)))  long  long2v;
typedef __attribute__((ext_vector_type(16))) float f32x16;

// ---- strip geometry: 64 cols/block, fp8 single K-pass ----
// seg strips: 157, 157, 469, 782  (bases 0, 157, 314, 783; total 1565)

// ---- workspace layout (bytes) ----
#define WS_FRAGS 0u           // fp8: 4 segs * 2048 * 512 * 1B = 4 MB (region 8 MB)
#define WS_LISTS 8388608u     // 4 * 2048 * 4B
#define WS_PART  8421376u     // 1565 * 2048 * 2B (bf16) = 6,410,240
#define WS_CUR   14843904u    // 16
#define WS_PAD   14843920u    // 16
#define WS_CL    14843936u    // 2048*3*4
#define WS_TGT   14868512u    // 2048*4
#define WS_ACC   14876704u    // 4*2049*4  (end 14,909,488)

__device__ __forceinline__ int cluster_of(int t){
  return (t < 10000) ? 0 : (t < 20000) ? 1 : (t < 50000) ? 2 : 3;
}
__device__ __forceinline__ bool is_root(int c){
  return c==5 || c==17 || c==123 || c==10005 || c==20007 || c==50011;
}
__device__ __forceinline__ unsigned short f2bf(float f){
  unsigned int u = __float_as_uint(f);
  u += 0x7fffu + ((u >> 16) & 1u);
  return (unsigned short)(u >> 16);
}
__device__ __forceinline__ float bf2f(unsigned short u){
  unsigned int v = ((unsigned int)u) << 16;
  return __uint_as_float(v);
}
__device__ __forceinline__ float fexp2(float x){
#if __has_builtin(__builtin_amdgcn_exp2f)
  return __builtin_amdgcn_exp2f(x);
#else
  return exp2f(x);
#endif
}
// f32 -> OCP e4m3fn, RNE, saturate to +-448, correct subnormals (2^-9 grid).
__device__ __forceinline__ unsigned int f2fp8(float x){
  unsigned int u = __float_as_uint(x);
  unsigned int s = (u >> 24) & 0x80u;
  float a = fabsf(x);
  if (!(a < 448.f)) return s | 0x7Eu;              // sat (and NaN -> max)
  if (a < 0.015625f){                              // < 2^-6: subnormal grid
    int m = __float2int_rn(a * 512.0f);            // 0..8 (8 == 2^-6 normal)
    return s | (unsigned int)m;
  }
  unsigned int au = u & 0x7FFFFFFFu;
  au += 0x7FFFFu + ((au >> 20) & 1u);              // RNE to 3 mantissa bits
  int e = (int)(au >> 23) - 127;                   // [-6, 8] after rounding
  unsigned int m = (au >> 20) & 7u;
  unsigned int enc = ((unsigned int)(e + 7) << 3) | m;
  if (enc > 0x7Eu) enc = 0x7Eu;                    // never emit NaN encoding
  return s | enc;
}
// pack float4 -> 4 fp8 bytes (HW cvt_pk when available: 2 instrs vs ~48)
__device__ __forceinline__ unsigned int fp8pk4(float x, float y, float z, float w){
#if __has_builtin(__builtin_amdgcn_cvt_pk_fp8_f32)
  int r = __builtin_amdgcn_cvt_pk_fp8_f32(x, y, 0, false);   // bytes 0,1
  r     = __builtin_amdgcn_cvt_pk_fp8_f32(z, w, r, true);    // bytes 2,3
  return (unsigned int)r;
#else
  return f2fp8(x) | (f2fp8(y)<<8) | (f2fp8(z)<<16) | (f2fp8(w)<<24);
#endif
}

// ---------------------------------------------------------------------------
// K1 (+list build merged): per-token cluster logits + exact-f32 target logit;
// lane 0 appends the token to its segment list.
// ---------------------------------------------------------------------------
__global__ void k_token_logits(const float* __restrict__ hidden,
                               const float* __restrict__ weight,
                               const float* __restrict__ bias,
                               const float* __restrict__ cw,
                               const float* __restrict__ cb,
                               const int*   __restrict__ target,
                               float* __restrict__ cl_out,   // [2048][3]
                               float* __restrict__ tgt_out,  // [2048]
                               int*   __restrict__ lists,
                               int*   __restrict__ cursors)
{
  int wave = threadIdx.x >> 6;
  int lane = threadIdx.x & 63;
  int n = blockIdx.x * 4 + wave;
  if (n >= NTOK) return;
  const float* h = hidden + (size_t)n * D + lane * 8;
  int t = target[n];
  const float* wt = weight + (size_t)t * D + lane * 8;
  float hv[8];
  #pragma unroll
  for (int i = 0; i < 8; ++i) hv[i] = h[i];
  float acc[4] = {0.f, 0.f, 0.f, 0.f};
  #pragma unroll
  for (int j = 0; j < 3; ++j){
    const float* cwj = cw + j * D + lane * 8;
    float s = 0.f;
    #pragma unroll
    for (int i = 0; i < 8; ++i) s += hv[i] * cwj[i];
    acc[j] = s;
  }
  {
    float s = 0.f;
    #pragma unroll
    for (int i = 0; i < 8; ++i) s += hv[i] * wt[i];
    acc[3] = s;
  }
  #pragma unroll
  for (int m = 1; m < 64; m <<= 1){
    #pragma unroll
    for (int j = 0; j < 4; ++j) acc[j] += __shfl_xor(acc[j], m, 64);
  }
  if (lane == 0){
    cl_out[n*3+0] = acc[0] + cb[0];
    cl_out[n*3+1] = acc[1] + cb[1];
    cl_out[n*3+2] = acc[2] + cb[2];
    float tg = acc[3] + bias[t];
    if (is_root(t)) tg = -INFINITY;
    tgt_out[n] = tg;
    lists[n] = n;
    int c = cluster_of(t);
    if (c > 0){
      int pos = atomicAdd(cursors + c, 1);
      lists[c * 2048 + pos] = n;
    }
  }
}

// ---------------------------------------------------------------------------
// K3: pad lists to multiples of 256 with sentinel token (=NTOK), write counts.
// ---------------------------------------------------------------------------
__global__ void k_pad_lists(int* __restrict__ lists, const int* __restrict__ cursors,
                            int* __restrict__ padded)
{
  if (threadIdx.x == 0) padded[0] = NTOK;
  for (int s = 1; s < 4; ++s){
    int c = cursors[s];
    int p = (c + 255) & ~255;
    if (threadIdx.x == 0) padded[s] = p;
    for (int i = c + threadIdx.x; i < p; i += blockDim.x)
      lists[s * 2048 + i] = NTOK;
  }
}

// ---------------------------------------------------------------------------
// K4: build fp8 A-fragments (hidden scaled by LOG2E so exp(x)=exp2(acc)).
// Layout (2 ks packed per 16B): byte off = ((mf*16 + kp)*64 + lane)*16,
// bytes[0..7] = ks=2kp (k = 32kp + hi*8 + j), bytes[8..15] = ks=2kp+1.
// HW cvt_pk_fp8 conversion (was the VALU hotspot at 12 ops/element).
// ---------------------------------------------------------------------------
__global__ void k_build_frags(const float* __restrict__ hidden,
                              const int*   __restrict__ lists,
                              const int*   __restrict__ padded,
                              unsigned char* __restrict__ frags)
{
  int tg   = blockIdx.x * 256 + threadIdx.x;   // [0, 4*65536)
  int seg  = tg >> 16;
  int s    = tg & 65535;
  int lane = s & 63;
  int kp   = (s >> 6) & 15;
  int mf   = s >> 10;                          // 0..63
  int row  = mf * 32 + (lane & 31);
  if (row >= padded[seg]) return;
  int token = lists[seg * 2048 + row];
  int hi    = lane >> 5;
  unsigned int w[4] = {0u, 0u, 0u, 0u};
  if (token < NTOK){
    const float* h0 = hidden + (size_t)token * D + 32 * kp + hi * 8;        // ks=2kp
    float4 a0 = *(const float4*)(h0);
    float4 a1 = *(const float4*)(h0 + 4);
    float4 b0 = *(const float4*)(h0 + 16);                                  // ks=2kp+1
    float4 b1 = *(const float4*)(h0 + 20);
    w[0] = fp8pk4(a0.x*LOG2E, a0.y*LOG2E, a0.z*LOG2E, a0.w*LOG2E);
    w[1] = fp8pk4(a1.x*LOG2E, a1.y*LOG2E, a1.z*LOG2E, a1.w*LOG2E);
    w[2] = fp8pk4(b0.x*LOG2E, b0.y*LOG2E, b0.z*LOG2E, b0.w*LOG2E);
    w[3] = fp8pk4(b1.x*LOG2E, b1.y*LOG2E, b1.z*LOG2E, b1.w*LOG2E);
  }
  size_t off = (size_t)seg * 1048576u + (((size_t)(mf * 16 + kp)) * 64 + lane) * 16;
  uint4 val; val.x = w[0]; val.y = w[1]; val.z = w[2]; val.w = w[3];
  *(uint4*)(frags + off) = val;
}

// ---------------------------------------------------------------------------
// K5: Σexp GEMM, fp8 (mfma_f32_32x32x16_fp8_fp8). Swapped operands (reg axis
// = weight col, lane = token); bias·LOG2E folded as extra all-ones-A MFMA
// (masked cols -448 -> exp2 -> 0). Per kp-step: 2 global A-loads + 2 LDS
// B-reads + 8 MFMAs. Bs-only LDS 34 KB -> 4 blocks/CU. Direct bf16 partials
// store. B staging now uses HW cvt_pk_fp8 (r25: scalar f2fp8 drove VALUBusy
// to 27.6% ~= MfmaUtil; dominant cost for the short-M tail blocks).
// ---------------------------------------------------------------------------
__device__ __forceinline__ void epi2(const f32x16& a, const f32x16& b, int r0,
                                     int lane, unsigned short* __restrict__ pp)
{
  float s = 0.f;
  #pragma unroll
  for (int r = 0; r < 16; ++r) s += fexp2(a[r]) + fexp2(b[r]);
  s += __shfl_xor(s, 32, 64);       // combine the two reg-row halves
  if (lane < 32)
    pp[r0 + lane] = f2bf(s);        // write-once: direct bf16 partials store
}

__global__ __launch_bounds__(512, 4)
void k_gemm(const unsigned char* __restrict__ frags,
            const float* __restrict__ weight,
            const float* __restrict__ bias,
            const int*   __restrict__ padded,
            unsigned short* __restrict__ partials)   // [1565][2048] bf16
{
  __shared__ unsigned char Bs[34816];          // 34 KB: 16 kp * 2048 + bias 2048

  int bid = blockIdx.x;
  int seg, strip0, colstart, colend;
  if      (bid < 157) { seg = 0; strip0 = 0;    colstart = 0;     colend = 10000;  }
  else if (bid < 314) { seg = 1; strip0 = 157;  colstart = 10000; colend = 20000;  }
  else if (bid < 783) { seg = 2; strip0 = 314;  colstart = 20000; colend = 50000;  }
  else                { seg = 3; strip0 = 783;  colstart = 50000; colend = 100000; }
  int col_base = colstart + (bid - strip0) * 64;

  int tid   = threadIdx.x;
  int wave  = tid >> 6;            // 0..7
  int lane  = tid & 63;
  int M = padded[seg];
  const unsigned char* fseg = frags + (size_t)seg * 1048576u;
  unsigned short* pp = partials + (size_t)bid * 2048;

  // ---- load B strip: 64 cols x 512 k, f32 -> fp8 (HW cvt), frag-native LDS ----
  for (int it = 0; it < 16; ++it){
    int id  = it * 512 + tid;               // [0, 8192)
    int col = id >> 7;                      // 0..63
    int k0  = (id & 127) * 4;               // 0..508
    int cg  = col_base + col;
    float4 v = make_float4(0.f, 0.f, 0.f, 0.f);
    if (cg < colend) v = *(const float4*)(weight + (size_t)cg * D + k0);
    unsigned int pk = fp8pk4(v.x, v.y, v.z, v.w);
    int ks = k0 >> 4, kp = ks >> 1, ksub = ks & 1, kk = k0 & 15;
    int hi2 = kk >> 3, j0 = kk & 7;         // j0 in {0,4}
    int off = kp * 2048 + (col >> 5) * 1024 + ((col & 31) + 32 * hi2) * 16 + ksub * 8 + j0;
    *(unsigned int*)(Bs + off) = pk;
  }
  // ---- stage bias slot (region [32768, 34816)): 16B per (col, hi-part) ----
  if (tid < 128){
    int col  = tid & 63;
    int part = tid >> 6;                    // 0: k 0-7 slot (bias at j=0); 1: k 8-15 (zeros)
    int cg   = col_base + col;
    unsigned int x = 0u;
    if (part == 0){
      float bv = (cg < colend && !is_root(cg)) ? bias[cg] * LOG2E : -448.f;
      x = f2fp8(bv);                        // low byte; rest zero (exact -448 path)
    }
    int off = 32768 + (col >> 5) * 1024 + ((col & 31) + 32 * part) * 16;
    uint4 z; z.x = x; z.y = 0u; z.z = 0u; z.w = 0u;
    *(uint4*)(Bs + off) = z;
  }
  __syncthreads();   // B + bias ready

  const char* bsc = (const char*)Bs;
  int l16 = lane * 16;
  long ones8 = 0x3838383838383838L;         // 8x fp8 e4m3 1.0

  for (int m0 = 0; m0 < M; m0 += 512){
    int r0 = m0 + wave * 64;
    if (r0 < M){
      f32x16 acc00, acc01, acc10, acc11;
      #pragma unroll
      for (int i = 0; i < 16; ++i){ acc00[i]=0.f; acc01[i]=0.f; acc10[i]=0.f; acc11[i]=0.f; }

      const unsigned char* pa0 = fseg + (size_t)(r0 >> 5) * 16384 + (size_t)lane * 16;
      const unsigned char* pa1 = pa0 + 16384;

      __builtin_amdgcn_s_setprio(1);
      #pragma unroll 4
      for (int kp = 0; kp < 16; ++kp){
        long2v A0 = *(const long2v*)(pa0 + kp * 1024);
        long2v A1 = *(const long2v*)(pa1 + kp * 1024);
        long2v B0 = *(const long2v*)(bsc + kp * 2048 + l16);
        long2v B1 = *(const long2v*)(bsc + kp * 2048 + 1024 + l16);
        acc00 = __builtin_amdgcn_mfma_f32_32x32x16_fp8_fp8(B0[0], A0[0], acc00, 0, 0, 0);
        acc01 = __builtin_amdgcn_mfma_f32_32x32x16_fp8_fp8(B1[0], A0[0], acc01, 0, 0, 0);
        acc10 = __builtin_amdgcn_mfma_f32_32x32x16_fp8_fp8(B0[0], A1[0], acc10, 0, 0, 0);
        acc11 = __builtin_amdgcn_mfma_f32_32x32x16_fp8_fp8(B1[0], A1[0], acc11, 0, 0, 0);
        acc00 = __builtin_amdgcn_mfma_f32_32x32x16_fp8_fp8(B0[1], A0[1], acc00, 0, 0, 0);
        acc01 = __builtin_amdgcn_mfma_f32_32x32x16_fp8_fp8(B1[1], A0[1], acc01, 0, 0, 0);
        acc10 = __builtin_amdgcn_mfma_f32_32x32x16_fp8_fp8(B0[1], A1[1], acc10, 0, 0, 0);
        acc11 = __builtin_amdgcn_mfma_f32_32x32x16_fp8_fp8(B1[1], A1[1], acc11, 0, 0, 0);
      }
      // bias step: Σ_k biasRow[c][k] * 1 = bias_c*LOG2E (or -448)
      {
        long bb0 = *(const long*)(bsc + 32768 + l16);
        long bb1 = *(const long*)(bsc + 32768 + 1024 + l16);
        acc00 = __builtin_amdgcn_mfma_f32_32x32x16_fp8_fp8(bb0, ones8, acc00, 0, 0, 0);
        acc01 = __builtin_amdgcn_mfma_f32_32x32x16_fp8_fp8(bb1, ones8, acc01, 0, 0, 0);
        acc10 = __builtin_amdgcn_mfma_f32_32x32x16_fp8_fp8(bb0, ones8, acc10, 0, 0, 0);
        acc11 = __builtin_amdgcn_mfma_f32_32x32x16_fp8_fp8(bb1, ones8, acc11, 0, 0, 0);
      }
      __builtin_amdgcn_s_setprio(0);
      epi2(acc00, acc01, r0,      lane, pp);   // tokens r0..r0+31
      epi2(acc10, acc11, r0 + 32, lane, pp);   // tokens r0+32..r0+63
    }
  }
}

// ---------------------------------------------------------------------------
// K5b: reduce bf16 partials over strips of each segment, scatter via lists.
// ---------------------------------------------------------------------------
__global__ void k_reduce(const unsigned short* __restrict__ partials,
                         const int*   __restrict__ lists,
                         const int*   __restrict__ padded,
                         float* __restrict__ acc_out)     // [4][2049]
{
  int b   = blockIdx.x;          // 32 blocks: seg = b>>3, row chunk = b&7
  int seg = b >> 3;
  int row = (b & 7) * 256 + threadIdx.x;
  if (row >= padded[seg]) return;
  int base, cnt;
  if      (seg == 0){ base = 0;   cnt = 157; }
  else if (seg == 1){ base = 157; cnt = 157; }
  else if (seg == 2){ base = 314; cnt = 469; }
  else              { base = 783; cnt = 782; }
  float s = 0.f;
  int j = 0;
  for (; j + 4 <= cnt; j += 4){
    s += bf2f(partials[(size_t)(base + j    ) * 2048 + row]);
    s += bf2f(partials[(size_t)(base + j + 1) * 2048 + row]);
    s += bf2f(partials[(size_t)(base + j + 2) * 2048 + row]);
    s += bf2f(partials[(size_t)(base + j + 3) * 2048 + row]);
  }
  for (; j < cnt; ++j) s += bf2f(partials[(size_t)(base + j) * 2048 + row]);
  int token = lists[seg * 2048 + row];
  if (token < NTOK) acc_out[seg * 2049 + token] = s;
}

// ---------------------------------------------------------------------------
// K6: finalize NLL per token.
// ---------------------------------------------------------------------------
__global__ void k_finalize(const float* __restrict__ accs,   // [4][2049]
                           const float* __restrict__ cl,     // [2048][3]
                           const float* __restrict__ tgt,
                           const int*   __restrict__ target,
                           float* __restrict__ out)
{
  int n = blockIdx.x * blockDim.x + threadIdx.x;
  if (n >= NTOK) return;
  int c = cluster_of(target[n]);
  float e0 = __expf(cl[n*3+0]), e1 = __expf(cl[n*3+1]), e2 = __expf(cl[n*3+2]);
  float head_lse = __logf(accs[n] + e0 + e1 + e2);
  float nll;
  if (c == 0){
    nll = head_lse - tgt[n];
  } else {
    float tail_lse = __logf(accs[c * 2049 + n]);
    nll = head_lse + tail_lse - cl[n*3 + (3 - c)] - tgt[n];
  }
  out[n] = nll;
}

extern "C" void kernel_launch(void* const* d_in, const int* in_sizes, int n_in,
                              void* d_out, int out_size, void* d_ws, size_t ws_size,
                              hipStream_t stream)
{
  (void)in_sizes; (void)n_in; (void)out_size; (void)ws_size;
  const float* hidden = (const float*)d_in[0];
  const float* weight = (const float*)d_in[1];
  const float* bias   = (const float*)d_in[2];
  const float* cw     = (const float*)d_in[3];
  const float* cb     = (const float*)d_in[4];
  const int*   target = (const int*)d_in[5];
  float* out = (float*)d_out;
  char*  ws  = (char*)d_ws;

  unsigned char*  frags    = (unsigned char*)(ws + WS_FRAGS);
  int*   lists    = (int*)(ws + WS_LISTS);
  unsigned short* partials = (unsigned short*)(ws + WS_PART);
  int*   cursors  = (int*)(ws + WS_CUR);
  int*   padded   = (int*)(ws + WS_PAD);
  float* cl       = (float*)(ws + WS_CL);
  float* tgt      = (float*)(ws + WS_TGT);
  float* acc      = (float*)(ws + WS_ACC);

  hipMemsetAsync(ws + WS_CUR, 0, 16, stream);   // cursors only

  k_token_logits<<<512, 256, 0, stream>>>(hidden, weight, bias, cw, cb, target,
                                          cl, tgt, lists, cursors);
  k_pad_lists   <<<1,   256, 0, stream>>>(lists, cursors, padded);
  k_build_frags <<<1024,256, 0, stream>>>(hidden, lists, padded, frags);
  k_gemm        <<<1565,512, 0, stream>>>(frags, weight, bias, padded, partials);
  k_reduce      <<<32,  256, 0, stream>>>(partials, lists, padded, acc);
  k_finalize    <<<8,   256, 0, stream>>>(acc, cl, tgt, target, out);
}